// Round 2
// 797.726 us; speedup vs baseline: 1.0318x; 1.0318x over previous
//
#include <hip/hip_runtime.h>
#include <cstdint>

#define H 256
#define MT 64

typedef _Float16 half8 __attribute__((ext_vector_type(8)));
typedef float floatx4 __attribute__((ext_vector_type(4)));

__device__ __forceinline__ float fast_tanh(float v) {
    v = fminf(fmaxf(v, -15.f), 15.f);
    float e = __expf(2.f * v);
    return (e - 1.f) / (e + 1.f);
}

// -------- setup: W1 [k][n] fp32 -> w1c f16 fragment order, and segment
// boundaries start[g] = lower_bound(batch, g) from the sorted batch array.
// w1c chunk t = ((ct*4 + s)*2 + kc), each 512 halves laid out [lane][h]:
//   element = W1[k = s*64 + kc*32 + (lane>>4)*8 + h][n = ct*16 + (lane&15)]
__global__ void setup_kernel(const float* __restrict__ W1,
                             _Float16* __restrict__ w1c,
                             const int* __restrict__ batch,
                             int* __restrict__ start, int N, int G,
                             int total) {
    for (int i = blockIdx.x * 256 + threadIdx.x; i < total;
         i += gridDim.x * 256) {
        if (i < H * H) {
            int r = i & 511;
            int lane = r >> 3, h = r & 7;
            int t = i >> 9;
            int kc = t & 1, s = (t >> 1) & 3, ct = t >> 3;
            int mm = lane & 15, qq = lane >> 4;
            int col = ct * 16 + mm;
            int k = s * 64 + kc * 32 + qq * 8 + h;
            w1c[i] = (_Float16)W1[k * H + col];
        }
        if (i < N) {
            int b = batch[i];
            int prev = (i > 0) ? batch[i - 1] : -1;
            for (int g = prev + 1; g <= b; ++g) start[g] = i;
            if (i == N - 1)
                for (int g = b + 1; g <= G; ++g) start[g] = N;
        }
    }
}

// -------- score kernel: w[row] = exp( w2 . tanh(x[row]@W1 + b1) ) -----------
// 256 thr (4 waves), tile 64 rows x 256 cols. Full-K staging (one barrier),
// b1 folded into the MFMA accumulator init. No Phase B, no atomics.
__global__ __launch_bounds__(256, 3) void score_kernel(
    const float* __restrict__ x, const _Float16* __restrict__ w1c,
    const float* __restrict__ b1, const float* __restrict__ w2,
    float* __restrict__ wexp, int N) {
    __shared__ _Float16 As[64][256];
    __shared__ float sred[4][64];

    const int tid = threadIdx.x;
    const int wv = tid >> 6;
    const int lane = tid & 63;
    const int m = lane & 15;
    const int q = lane >> 4;
    const int row0 = blockIdx.x * MT;

    const int srow = tid >> 2;
    const int sc4 = tid & 3;
    const bool srok = (row0 + srow) < N;
    const float* sbase = x + (size_t)(row0 + srow) * H + sc4 * 16;
    const int sg0 = (sc4 * 2) ^ (srow & 7);       // swizzled 8-half groups
    const int sg1 = (sc4 * 2 + 1) ^ (srow & 7);

    float b1c[4], w2c[4];
#pragma unroll
    for (int ni = 0; ni < 4; ++ni) {
        int c = wv * 64 + ni * 16 + m;
        b1c[ni] = b1[c];
        w2c[ni] = w2[c];
    }

    // stage the full 64x256 tile as fp16 into swizzled LDS (single barrier;
    // 16 independent float4 loads per thread -> deep VMEM pipelining)
    if (srok) {
#pragma unroll
        for (int s = 0; s < 4; ++s) {
            const float4* p = (const float4*)(sbase + s * 64);
            float4 f0 = p[0], f1 = p[1], f2 = p[2], f3 = p[3];
            half8 h0, h1;
            h0[0] = (_Float16)f0.x; h0[1] = (_Float16)f0.y; h0[2] = (_Float16)f0.z; h0[3] = (_Float16)f0.w;
            h0[4] = (_Float16)f1.x; h0[5] = (_Float16)f1.y; h0[6] = (_Float16)f1.z; h0[7] = (_Float16)f1.w;
            h1[0] = (_Float16)f2.x; h1[1] = (_Float16)f2.y; h1[2] = (_Float16)f2.z; h1[3] = (_Float16)f2.w;
            h1[4] = (_Float16)f3.x; h1[5] = (_Float16)f3.y; h1[6] = (_Float16)f3.z; h1[7] = (_Float16)f3.w;
            *(half8*)&As[srow][s * 64 + sg0 * 8] = h0;
            *(half8*)&As[srow][s * 64 + sg1 * 8] = h1;
        }
    }

    floatx4 acc[4][4];
#pragma unroll
    for (int mi = 0; mi < 4; ++mi)
#pragma unroll
        for (int ni = 0; ni < 4; ++ni) {
            floatx4 v;
            v[0] = b1c[ni]; v[1] = b1c[ni]; v[2] = b1c[ni]; v[3] = b1c[ni];
            acc[mi][ni] = v;
        }

    __syncthreads();

    for (int s = 0; s < 4; ++s) {
        // B fragments: fully coalesced 16B/lane from L2-resident w1c
        half8 bf[4][2];
#pragma unroll
        for (int ni = 0; ni < 4; ++ni) {
            int ct = wv * 4 + ni;
#pragma unroll
            for (int kc = 0; kc < 2; ++kc) {
                int chunk = ((ct << 2) | s) * 2 + kc;
                bf[ni][kc] = *(const half8*)(w1c + ((size_t)chunk << 9) + lane * 8);
            }
        }
        // A fragments from swizzled LDS (read-only after the one barrier)
        half8 af[4][2];
#pragma unroll
        for (int mi = 0; mi < 4; ++mi) {
            int r = mi * 16 + m;
#pragma unroll
            for (int kc = 0; kc < 2; ++kc) {
                int g = (kc * 4 + q) ^ (r & 7);
                af[mi][kc] = *(const half8*)&As[r][s * 64 + g * 8];
            }
        }
#pragma unroll
        for (int mi = 0; mi < 4; ++mi)
#pragma unroll
            for (int ni = 0; ni < 4; ++ni) {
                acc[mi][ni] = __builtin_amdgcn_mfma_f32_16x16x32_f16(
                    af[mi][0], bf[ni][0], acc[mi][ni], 0, 0, 0);
                acc[mi][ni] = __builtin_amdgcn_mfma_f32_16x16x32_f16(
                    af[mi][1], bf[ni][1], acc[mi][ni], 0, 0, 0);
            }
    }

    // epilogue: s_row = sum_j w2[j] * tanh(h[row][j])   (b1 already in acc)
#pragma unroll
    for (int mi = 0; mi < 4; ++mi) {
#pragma unroll
        for (int r = 0; r < 4; ++r) {
            float v = 0.f;
#pragma unroll
            for (int ni = 0; ni < 4; ++ni)
                v += w2c[ni] * fast_tanh(acc[mi][ni][r]);
            v += __shfl_xor(v, 1);
            v += __shfl_xor(v, 2);
            v += __shfl_xor(v, 4);
            v += __shfl_xor(v, 8);
            if (m == 0) sred[wv][mi * 16 + q * 4 + r] = v;
        }
    }
    __syncthreads();
    if (tid < MT) {
        int row = row0 + tid;
        if (row < N) {
            float sc = sred[0][tid] + sred[1][tid] + sred[2][tid] + sred[3][tid];
            wexp[row] = __expf(sc);   // |sc| <= sum|w2| ~ 13: no overflow
        }
    }
}

// -------- segment kernel: one wave per graph, contiguous sorted rows --------
// Thread = (wave, lane); lane owns 4 columns (float4 loads, 16B/lane).
// No atomics: each graph's rows are a contiguous [lo, hi) span; normalize
// inline and store the final output directly.
__global__ __launch_bounds__(256, 4) void seg_kernel(
    const float* __restrict__ x, const float* __restrict__ wexp,
    const int* __restrict__ start, float4* __restrict__ out4, int G) {
    const int wv = threadIdx.x >> 6;
    const int lane = threadIdx.x & 63;
    const int g = blockIdx.x * 4 + wv;
    if (g >= G) return;
    const int lo = start[g];
    const int hi = start[g + 1];
    const float4* px = (const float4*)x + lane;
    float4 a = make_float4(0.f, 0.f, 0.f, 0.f);
    float z = 0.f;
#pragma unroll 4
    for (int r = lo; r < hi; ++r) {
        float w = wexp[r];                       // wave-uniform broadcast load
        float4 v = px[(size_t)r * (H / 4)];      // full row per wave, coalesced
        z += w;
        a.x = fmaf(w, v.x, a.x);
        a.y = fmaf(w, v.y, a.y);
        a.z = fmaf(w, v.z, a.z);
        a.w = fmaf(w, v.w, a.w);
    }
    float inv = (hi > lo) ? 1.f / z : 0.f;       // empty graph -> zeros
    a.x *= inv; a.y *= inv; a.z *= inv; a.w *= inv;
    out4[(size_t)g * (H / 4) + lane] = a;
}

extern "C" void kernel_launch(void* const* d_in, const int* in_sizes, int n_in,
                              void* d_out, int out_size, void* d_ws, size_t ws_size,
                              hipStream_t stream) {
    const float* x = (const float*)d_in[0];
    const int* batch = (const int*)d_in[1];
    const float* W1 = (const float*)d_in[2];
    const float* b1 = (const float*)d_in[3];
    const float* w2 = (const float*)d_in[4];
    float* out = (float*)d_out;

    const int N = in_sizes[0] / H;
    const int G = out_size / H;

    // workspace: w1c (128 KB) | start[G+1] | wexp[N]
    char* ws = (char*)d_ws;
    _Float16* w1c = (_Float16*)ws;
    int* start = (int*)(ws + (size_t)H * H * sizeof(_Float16));
    size_t off = (size_t)H * H * sizeof(_Float16) + (size_t)(G + 1) * sizeof(int);
    off = (off + 15) & ~(size_t)15;
    float* wexp = (float*)(ws + off);

    int setup_items = (N > H * H) ? N : (H * H);
    int setup_blocks = (setup_items + 255) / 256;
    if (setup_blocks > 2048) setup_blocks = 2048;
    setup_kernel<<<setup_blocks, 256, 0, stream>>>(
        W1, w1c, batch, start, N, G, setup_items);
    score_kernel<<<(N + MT - 1) / MT, 256, 0, stream>>>(
        x, w1c, b1, w2, wexp, N);
    seg_kernel<<<(G + 3) / 4, 256, 0, stream>>>(
        x, wexp, start, (float4*)out, G);
}